// Round 1
// baseline (362.210 us; speedup 1.0000x reference)
//
#include <hip/hip_runtime.h>

// SpectralPooling: out[b,c,nd,nh,w] = sum_{d,h} A[nd,d]*A[nh,h]*x[b,c,d,h,w]  (w<32)
// where A = C32^T @ C64[:32,:] (32x64). The B-axis forward+inverse 8-pt DCT is
// C8^T C8 = I (orthonormal) and is skipped exactly.
//
// R5: phase-overlap restructure. R4 had 1 block/CU (135 KB LDS) + 4 full-block
// barriers -> HBM idle during every stage-2/epilogue phase. Now:
//  - w is a pure batch axis (no W-DCT, only w<32 kept) -> split each (b,c)
//    into two 16-wide w-halves: 512 blocks x 512 threads, LDS 70.7 KB,
//    2 blocks/CU. Sibling blocks are bid and bid+256 -> same XCD under %8
//    round-robin, so the two 64B halves of each 128B x-line are one HBM fetch
//    via shared L2.
//  - cross-cc register prefetch: cc=1's first 32 x-loads issue at cc=0's
//    stage-2 entry (xa/xc are dead there) -> HBM stays busy under stage-2
//    even if the sibling blocks phase-lock.
//  - LDS layout: flat, nh-stride 17, d-stride 552 (== 8 mod 32): stage-1
//    writes (4 d-groups x 16 w) and stage-2 float2 reads both land at free
//    2-way bank aliasing. Final barrier dropped.
// Arithmetic order is IDENTICAL to R4 (same h-group order, same dd order),
// so the result is bit-identical (absmax 0.015625 preserved).

// ---------- compile-time DCT-product table ----------
constexpr double kPI = 3.14159265358979323846;

constexpr double cos_poly(double x) {  // |x| <= pi, ~1e-16
  double r = 1.0;
  for (int k = 15; k >= 1; --k) r = 1.0 - r * x * x / ((2.0 * k) * (2.0 * k - 1.0));
  return r;
}
constexpr double csqrt(double v) {
  double r = (v > 1.0) ? v : 1.0;
  for (int i = 0; i < 64; ++i) r = 0.5 * (r + v / r);
  return r;
}

struct C64T  { double c[128]; };
struct C128T { double c[256]; };
constexpr C64T make_c64() {   // c[m] = cos(pi*m/64), integer-exact reduction
  C64T t{};
  for (int m = 0; m < 128; ++m) {
    int mm = (m > 64) ? m - 128 : m;
    t.c[m] = cos_poly(kPI * (double)mm / 64.0);
  }
  return t;
}
constexpr C128T make_c128() {  // c[m] = cos(pi*m/128)
  C128T t{};
  for (int m = 0; m < 256; ++m) {
    int mm = (m > 128) ? m - 256 : m;
    t.c[m] = cos_poly(kPI * (double)mm / 128.0);
  }
  return t;
}
constexpr C64T  C64_  = make_c64();
constexpr C128T C128_ = make_c128();

struct ATabH { float a[16 * 64]; };  // split in halves: constexpr step budget
constexpr ATabH make_A_half(int n0) {
  ATabH t{};
  const double s32a = csqrt(1.0 / 32.0), s32b = csqrt(2.0 / 32.0);
  const double s64a = csqrt(1.0 / 64.0), s64b = csqrt(2.0 / 64.0);
  for (int ni = 0; ni < 16; ++ni)
    for (int h = 0; h < 64; ++h) {
      const int n = n0 + ni;
      double s = 0.0;
      for (int k = 0; k < 32; ++k) {
        double sc = ((k == 0) ? s32a : s32b) * ((k == 0) ? s64a : s64b);
        s += sc * C64_.c[((2 * n + 1) * k) % 128] * C128_.c[((2 * h + 1) * k) % 256];
      }
      t.a[ni * 64 + h] = (float)s;
    }
  return t;
}
constexpr ATabH A_LO = make_A_half(0);
constexpr ATabH A_HI = make_A_half(16);

__host__ __device__ constexpr float Aval(int n, int h) {  // folds after unroll
  return (n < 16) ? A_LO.a[n * 64 + h] : A_HI.a[(n - 16) * 64 + h];
}

// Stage-2 table, reordered so each wave's per-chunk slice is contiguous:
// AT2[ndg][dg][i] = A[ndg*4+i][dg]   (ndg = wave's nd group, 0..7)
struct AT2Tab { float a[8 * 64 * 4]; };
constexpr AT2Tab make_AT2() {
  AT2Tab t{};
  for (int ndg = 0; ndg < 8; ++ndg)
    for (int dg = 0; dg < 64; ++dg)
      for (int i = 0; i < 4; ++i)
        t.a[(ndg * 64 + dg) * 4 + i] = Aval(ndg * 4 + i, dg);
  return t;
}
__device__ const AT2Tab AT2_DEV = make_AT2();

// ---------- stage-1 helper: 16 h-steps, fully unrolled, A as literals ----------
template <int HB>
__device__ __forceinline__ void s1_group(float (&p)[32], const float (&xr)[16]) {
#pragma unroll
  for (int nh = 0; nh < 32; ++nh) {
    float s = p[nh];
#pragma unroll
    for (int i = 0; i < 16; ++i) s = fmaf(Aval(nh, HB + i), xr[i], s);
    p[nh] = s;
  }
}

// LDS geometry: V[d=0..31][nh=0..31][w=0..15], nh-stride 17 floats,
// d-stride 552 floats (552 mod 32 == 8 -> 2-way-free stage-1 writes).
#define NH_STR 17
#define D_STR  552

// 512 blocks (bc = bid&255, whalf = bid>>8), 512 threads = 8 waves.
__global__ __launch_bounds__(512, 4) void spectral_kernel(
    const float* __restrict__ x, float* __restrict__ out) {
  __shared__ float VS[32 * D_STR];  // 70656 B -> 2 blocks/CU

  const int tid = threadIdx.x;
  const int bid = blockIdx.x;
  const int bc = bid & 255;             // b*32 + c
  const int whalf = bid >> 8;           // 0 or 1: which 16-wide w half

  const int wv = tid >> 6;              // 0..7 = stage-2 nd group (wave-uniform)
  const int dloc = tid >> 4;            // 0..31 stage-1 d within chunk
  const int w = tid & 15;               // stage-1 w within half
  const int l = tid & 63;               // lane
  const int w8 = l & 7;                 // stage-2 float2 index (w pair)
  const int nhq = (l >> 3) & 3;         // stage-2 nh sub
  const int jg = l >> 5;                // stage-2 nh half (lane bit 5)

  const float* xb = x + (size_t)bc * 262144 + (whalf << 4);  // 64*64*64

  float acc[4][4][2];
#pragma unroll
  for (int i = 0; i < 4; ++i)
#pragma unroll
    for (int j = 0; j < 4; ++j) {
      acc[i][j][0] = 0.f;
      acc[i][j][1] = 0.f;
    }

  float xa[16], xc[16];
  {  // prologue: first 32 h-loads of cc=0
    const float* xcol = xb + (size_t)dloc * 4096 + w;
#pragma unroll
    for (int i = 0; i < 16; ++i) xa[i] = xcol[i * 64];
#pragma unroll
    for (int i = 0; i < 16; ++i) xc[i] = xcol[(16 + i) * 64];
  }

#pragma unroll 1
  for (int cc = 0; cc < 2; ++cc) {
    // ---- stage 1: p[nh] = sum_h A[nh,h]*x[d,h,w]; pure v_fmamk, no A loads
    const float* xcol = xb + (size_t)(cc * 32 + dloc) * 4096 + w;

    float p[32];
#pragma unroll
    for (int nh = 0; nh < 32; ++nh) p[nh] = 0.f;

    s1_group<0>(p, xa);                     // h 0..15 (preloaded)
#pragma unroll
    for (int i = 0; i < 16; ++i) xa[i] = xcol[(32 + i) * 64];
    s1_group<16>(p, xc);                    // h 16..31 (preloaded)
#pragma unroll
    for (int i = 0; i < 16; ++i) xc[i] = xcol[(48 + i) * 64];
    s1_group<32>(p, xa);
    s1_group<48>(p, xc);

#pragma unroll
    for (int nh = 0; nh < 32; ++nh) VS[dloc * D_STR + nh * NH_STR + w] = p[nh];
    __syncthreads();

    // ---- prefetch cc=1's first 32 h-loads into the now-dead xa/xc so HBM
    //      stays busy under stage-2 (uniform branch)
    if (cc == 0) {
      const float* xn = xb + (size_t)(32 + dloc) * 4096 + w;
#pragma unroll
      for (int i = 0; i < 16; ++i) xa[i] = xn[i * 64];
#pragma unroll
      for (int i = 0; i < 16; ++i) xc[i] = xn[(16 + i) * 64];
    }

    // ---- stage 2: acc[nd][nh][w] += A[nd,d] * V[d][nh][w]
    const float4* at4 = (const float4*)(AT2_DEV.a) + wv * 64 + cc * 32;
#pragma unroll 8
    for (int dd = 0; dd < 32; ++dd) {
      const float4 a4 = at4[dd];  // uniform address, batched x8
#pragma unroll
      for (int j = 0; j < 4; ++j) {
        const int nh = jg * 16 + j * 4 + nhq;
        const float2 v =
            *(const float2*)&VS[dd * D_STR + nh * NH_STR + w8 * 2];
        acc[0][j][0] = fmaf(a4.x, v.x, acc[0][j][0]);
        acc[0][j][1] = fmaf(a4.x, v.y, acc[0][j][1]);
        acc[1][j][0] = fmaf(a4.y, v.x, acc[1][j][0]);
        acc[1][j][1] = fmaf(a4.y, v.y, acc[1][j][1]);
        acc[2][j][0] = fmaf(a4.z, v.x, acc[2][j][0]);
        acc[2][j][1] = fmaf(a4.z, v.y, acc[2][j][1]);
        acc[3][j][0] = fmaf(a4.w, v.x, acc[3][j][0]);
        acc[3][j][1] = fmaf(a4.w, v.y, acc[3][j][1]);
      }
    }
    if (cc == 0) __syncthreads();  // protect V before cc=1 overwrites it
  }

  // ---- epilogue: out[bc, nd, nh, whalf*16 + w8*2 .. +1]
  float* ob = out + (size_t)bc * 32768 + (whalf << 4);
#pragma unroll
  for (int i = 0; i < 4; ++i) {
    const int nd = wv * 4 + i;
#pragma unroll
    for (int j = 0; j < 4; ++j) {
      const int nh = jg * 16 + j * 4 + nhq;
      float2 v;
      v.x = acc[i][j][0];
      v.y = acc[i][j][1];
      *(float2*)(ob + nd * 1024 + nh * 32 + w8 * 2) = v;
    }
  }
}

extern "C" void kernel_launch(void* const* d_in, const int* in_sizes, int n_in,
                              void* d_out, int out_size, void* d_ws, size_t ws_size,
                              hipStream_t stream) {
  const float* x = (const float*)d_in[0];
  spectral_kernel<<<512, 512, 0, stream>>>(x, (float*)d_out);
}

// Round 2
// 349.121 us; speedup vs baseline: 1.0375x; 1.0375x over previous
//
#include <hip/hip_runtime.h>

// SpectralPooling: out[b,c,nd,nh,w] = sum_{d,h} A[nd,d]*A[nh,h]*x[b,c,d,h,w]  (w<32)
// where A = C32^T @ C64[:32,:] (32x64). The B-axis forward+inverse 8-pt DCT is
// C8^T C8 = I (orthonormal) and is skipped exactly.
//
// R6: revert R5's w-split (64B segments risked 2x HBM fetch when sibling
// blocks land on different XCDs: measured +18us, matching doubled x traffic
// at 6.6 TB/s). Back to R4 geometry: 256 blocks x 1024 threads, full 32-wide
// w -> every wave load covers two 128B lines. Keep the two safe R5 ideas,
// both arithmetic-order-identical to R4:
//  - cross-cc register prefetch: cc=1's first 32 h-loads issue right after
//    the stage-1 barrier of cc=0, into the then-dead xa/xc registers, so HBM
//    read traffic continues under stage-2's FMA/LDS phase.
//  - final __syncthreads dropped (only cc0->cc1 V overwrite needs the fence).
// Result must be bit-identical to R4 (absmax 0.015625).

// ---------- compile-time DCT-product table ----------
constexpr double kPI = 3.14159265358979323846;

constexpr double cos_poly(double x) {  // |x| <= pi, ~1e-16
  double r = 1.0;
  for (int k = 15; k >= 1; --k) r = 1.0 - r * x * x / ((2.0 * k) * (2.0 * k - 1.0));
  return r;
}
constexpr double csqrt(double v) {
  double r = (v > 1.0) ? v : 1.0;
  for (int i = 0; i < 64; ++i) r = 0.5 * (r + v / r);
  return r;
}

struct C64T  { double c[128]; };
struct C128T { double c[256]; };
constexpr C64T make_c64() {   // c[m] = cos(pi*m/64), integer-exact reduction
  C64T t{};
  for (int m = 0; m < 128; ++m) {
    int mm = (m > 64) ? m - 128 : m;
    t.c[m] = cos_poly(kPI * (double)mm / 64.0);
  }
  return t;
}
constexpr C128T make_c128() {  // c[m] = cos(pi*m/128)
  C128T t{};
  for (int m = 0; m < 256; ++m) {
    int mm = (m > 128) ? m - 256 : m;
    t.c[m] = cos_poly(kPI * (double)mm / 128.0);
  }
  return t;
}
constexpr C64T  C64_  = make_c64();
constexpr C128T C128_ = make_c128();

struct ATabH { float a[16 * 64]; };  // split in halves: constexpr step budget
constexpr ATabH make_A_half(int n0) {
  ATabH t{};
  const double s32a = csqrt(1.0 / 32.0), s32b = csqrt(2.0 / 32.0);
  const double s64a = csqrt(1.0 / 64.0), s64b = csqrt(2.0 / 64.0);
  for (int ni = 0; ni < 16; ++ni)
    for (int h = 0; h < 64; ++h) {
      const int n = n0 + ni;
      double s = 0.0;
      for (int k = 0; k < 32; ++k) {
        double sc = ((k == 0) ? s32a : s32b) * ((k == 0) ? s64a : s64b);
        s += sc * C64_.c[((2 * n + 1) * k) % 128] * C128_.c[((2 * h + 1) * k) % 256];
      }
      t.a[ni * 64 + h] = (float)s;
    }
  return t;
}
constexpr ATabH A_LO = make_A_half(0);
constexpr ATabH A_HI = make_A_half(16);

__host__ __device__ constexpr float Aval(int n, int h) {  // folds after unroll
  return (n < 16) ? A_LO.a[n * 64 + h] : A_HI.a[(n - 16) * 64 + h];
}

// Stage-2 table, reordered so each wave's per-chunk slice is contiguous:
// AT2[ndg][dg][i] = A[ndg*4+i][dg]   (ndg = wave's nd group)
struct AT2Tab { float a[8 * 64 * 4]; };
constexpr AT2Tab make_AT2() {
  AT2Tab t{};
  for (int ndg = 0; ndg < 8; ++ndg)
    for (int dg = 0; dg < 64; ++dg)
      for (int i = 0; i < 4; ++i)
        t.a[(ndg * 64 + dg) * 4 + i] = Aval(ndg * 4 + i, dg);
  return t;
}
__device__ const AT2Tab AT2_DEV = make_AT2();  // runtime wave-indexed -> s_load

// ---------- stage-1 helper: 16 h-steps, fully unrolled, A as literals ----------
template <int HB>
__device__ __forceinline__ void s1_group(float (&p)[32], const float (&xr)[16]) {
#pragma unroll
  for (int nh = 0; nh < 32; ++nh) {
    float s = p[nh];
#pragma unroll
    for (int i = 0; i < 16; ++i) s = fmaf(Aval(nh, HB + i), xr[i], s);
    p[nh] = s;
  }
}

// One workgroup per (b,c): 1024 threads = 16 waves, 135 KB LDS -> 1 block/CU.
// Stage 1: thread (dloc = tid>>5, w = tid&31) owns one x column; h in 4
//   pipelined groups of 16 (16 coalesced dword loads in flight per group).
// Stage 2: wave -> (ndg = wv&7, jg = wv>>3), lane -> (nhq, w16); float2 LDS
//   reads (V padded to 33 -> 2-way max bank aliasing), acc[4 nd][4 nh][2 w].
__global__ __launch_bounds__(1024, 4) void spectral_kernel(
    const float* __restrict__ x, float* __restrict__ out) {
  __shared__ float V[32][32][33];  // 135 KB: [d_in_chunk][nh][w + pad]

  const int tid = threadIdx.x;
  const int bc = blockIdx.x;            // b*32 + c
  const int wv = tid >> 6;              // 0..15 (wave-uniform)
  const int dloc = tid >> 5;            // 0..31 stage-1 d within chunk
  const int w = tid & 31;               // stage-1 w
  const int nhq = (tid >> 4) & 3;       // stage-2 nh sub
  const int w16 = tid & 15;             // stage-2 w pair
  const int ndg = wv & 7;               // stage-2 nd group (wave-uniform)
  const int jg = wv >> 3;               // stage-2 nh half (wave-uniform)

  const float* xb = x + (size_t)bc * 262144;  // 64*64*64

  float acc[4][4][2];
#pragma unroll
  for (int i = 0; i < 4; ++i)
#pragma unroll
    for (int j = 0; j < 4; ++j) {
      acc[i][j][0] = 0.f;
      acc[i][j][1] = 0.f;
    }

  float xa[16], xc[16];
  {  // prologue: first 32 h-loads of cc=0 (identical values/order as R4)
    const float* xcol = xb + (size_t)dloc * 4096 + w;
#pragma unroll
    for (int i = 0; i < 16; ++i) xa[i] = xcol[i * 64];
#pragma unroll
    for (int i = 0; i < 16; ++i) xc[i] = xcol[(16 + i) * 64];
  }

#pragma unroll 1
  for (int cc = 0; cc < 2; ++cc) {
    // ---- stage 1: p[nh] = sum_h A[nh,h]*x[d,h,w]; pure v_fmamk, no A loads
    const float* xcol = xb + (size_t)(cc * 32 + dloc) * 4096 + w;

    float p[32];
#pragma unroll
    for (int nh = 0; nh < 32; ++nh) p[nh] = 0.f;

    s1_group<0>(p, xa);                     // h 0..15 (preloaded)
#pragma unroll
    for (int i = 0; i < 16; ++i) xa[i] = xcol[(32 + i) * 64];
    s1_group<16>(p, xc);                    // h 16..31 (preloaded)
#pragma unroll
    for (int i = 0; i < 16; ++i) xc[i] = xcol[(48 + i) * 64];
    s1_group<32>(p, xa);
    s1_group<48>(p, xc);

#pragma unroll
    for (int nh = 0; nh < 32; ++nh) V[dloc][nh][w] = p[nh];
    __syncthreads();

    // ---- prefetch cc=1's first 32 h-loads into the now-dead xa/xc so HBM
    //      read traffic continues under stage-2's FMA/LDS phase
    if (cc == 0) {
      const float* xn = xb + (size_t)(32 + dloc) * 4096 + w;
#pragma unroll
      for (int i = 0; i < 16; ++i) xa[i] = xn[i * 64];
#pragma unroll
      for (int i = 0; i < 16; ++i) xc[i] = xn[(16 + i) * 64];
    }

    // ---- stage 2: acc[nd][nh][w] += A[nd,d] * V[d][nh][w]
    const float4* at4 = (const float4*)(AT2_DEV.a) + ndg * 64 + cc * 32;
#pragma unroll 8
    for (int dd = 0; dd < 32; ++dd) {
      const float4 a4 = at4[dd];  // wave-uniform s_load_dwordx4, batched x8
#pragma unroll
      for (int j = 0; j < 4; ++j) {
        const int nh = (jg * 4 + j) * 4 + nhq;
        const float2 v = *(const float2*)&V[dd][nh][w16 * 2];
        acc[0][j][0] = fmaf(a4.x, v.x, acc[0][j][0]);
        acc[0][j][1] = fmaf(a4.x, v.y, acc[0][j][1]);
        acc[1][j][0] = fmaf(a4.y, v.x, acc[1][j][0]);
        acc[1][j][1] = fmaf(a4.y, v.y, acc[1][j][1]);
        acc[2][j][0] = fmaf(a4.z, v.x, acc[2][j][0]);
        acc[2][j][1] = fmaf(a4.z, v.y, acc[2][j][1]);
        acc[3][j][0] = fmaf(a4.w, v.x, acc[3][j][0]);
        acc[3][j][1] = fmaf(a4.w, v.y, acc[3][j][1]);
      }
    }
    if (cc == 0) __syncthreads();  // protect V before cc=1 overwrites it
  }

  // ---- epilogue: out[bc, nd, nh, w]; each (i,j) store covers 512 B contiguous
  float* ob = out + (size_t)bc * 32768;
#pragma unroll
  for (int i = 0; i < 4; ++i) {
    const int nd = ndg * 4 + i;
#pragma unroll
    for (int j = 0; j < 4; ++j) {
      const int nh = (jg * 4 + j) * 4 + nhq;
      float2 v;
      v.x = acc[i][j][0];
      v.y = acc[i][j][1];
      *(float2*)(ob + nd * 1024 + nh * 32 + w16 * 2) = v;
    }
  }
}

extern "C" void kernel_launch(void* const* d_in, const int* in_sizes, int n_in,
                              void* d_out, int out_size, void* d_ws, size_t ws_size,
                              hipStream_t stream) {
  const float* x = (const float*)d_in[0];
  spectral_kernel<<<256, 1024, 0, stream>>>(x, (float*)d_out);
}